// Round 5
// baseline (100.837 us; speedup 1.0000x reference)
//
#include <hip/hip_runtime.h>
#include <hip/hip_bf16.h>
#include <stdint.h>

#define S_LEN 2048
#define D_DIM 128
#define QT 128          // q rows per block (4 waves x 32)
#define KT 64           // k rows per tile
#define NT (S_LEN/KT)   // 32 tiles

typedef float  f32x4  __attribute__((ext_vector_type(4)));
typedef float  f32x16 __attribute__((ext_vector_type(16)));
typedef short  bf16x8 __attribute__((ext_vector_type(8)));
typedef unsigned int uintx4 __attribute__((ext_vector_type(4)));

__device__ __forceinline__ short f2bf(float f) {
    return __builtin_bit_cast(short, __float2bfloat16(f));
}

__device__ __forceinline__ unsigned int pk2(float lo, float hi) {
    unsigned int d;
    asm("v_cvt_pk_bf16_f32 %0, %1, %2" : "=v"(d) : "v"(lo), "v"(hi));
    return d;
}

__device__ __forceinline__ void gload_lds16(const short* g, char* l) {
    __builtin_amdgcn_global_load_lds(
        (const __attribute__((address_space(1))) void*)g,
        (__attribute__((address_space(3))) void*)l,
        16, 0, 0);
}

// ---------------------------------------------------------------------------
// Pre-pass 1: K fp32 -> bf16 row-major copy.
// ---------------------------------------------------------------------------
__global__ __launch_bounds__(256)
void convert_k_kernel(const float* __restrict__ kin, short* __restrict__ kbf) {
    const size_t i = ((size_t)blockIdx.x * 256 + threadIdx.x) * 8;
    f32x4 a = *(const f32x4*)(kin + i);
    f32x4 c = *(const f32x4*)(kin + i + 4);
    bf16x8 t;
    t[0]=f2bf(a[0]); t[1]=f2bf(a[1]); t[2]=f2bf(a[2]); t[3]=f2bf(a[3]);
    t[4]=f2bf(c[0]); t[5]=f2bf(c[1]); t[6]=f2bf(c[2]); t[7]=f2bf(c[3]);
    *(bf16x8*)(kbf + i) = t;
}

// ---------------------------------------------------------------------------
// Pre-pass 2: V fp32 [bh][k][d] -> bf16 transposed VT [bh][d][S_LEN].
// ---------------------------------------------------------------------------
__global__ __launch_bounds__(256)
void transpose_v_kernel(const float* __restrict__ vin, short* __restrict__ vt) {
    __shared__ short T[16 * 130];
    const int tid = threadIdx.x;
    const int blk = blockIdx.x;          // 256 = 32 bh * 8 dgroups
    const int bh  = blk >> 3;
    const int d0  = (blk & 7) * 16;
    const float* vb = vin + (size_t)bh * S_LEN * D_DIM;
    short* vtb = vt + (size_t)bh * (size_t)D_DIM * S_LEN;
    const int c4 = tid & 3;
    const int rr = tid >> 2;
    const int dl = tid >> 4;
    const int kc = tid & 15;

    for (int kc0 = 0; kc0 < S_LEN; kc0 += 128) {
        #pragma unroll
        for (int h = 0; h < 2; ++h) {
            const int krow = kc0 + h*64 + rr;
            f32x4 a = *(const f32x4*)(vb + (size_t)krow * D_DIM + d0 + c4*4);
            #pragma unroll
            for (int j = 0; j < 4; ++j)
                T[(c4*4 + j)*130 + h*64 + rr] = f2bf(a[j]);
        }
        __syncthreads();
        int w0 = *(const int*)&T[dl*130 + kc*8 + 0];
        int w1 = *(const int*)&T[dl*130 + kc*8 + 2];
        int w2 = *(const int*)&T[dl*130 + kc*8 + 4];
        int w3 = *(const int*)&T[dl*130 + kc*8 + 6];
        int4 val = make_int4(w0, w1, w2, w3);
        *(int4*)(vtb + (size_t)(d0 + dl) * S_LEN + kc0 + kc*8) = val;
        __syncthreads();
    }
}

// ---------------------------------------------------------------------------
// Main kernel: 32x32x16 MFMA, swapped QK^T, in-register P (cvt_pk+permlane),
// FRAGMENT-MAJOR LDS layouts:
//   K tile: slot((kf*8+dk)*2+hi, l31) -> K[kf*32+l31][ (dk*2+hi)*8 ..+8 ]
//   V tile: slot((df*4+ks)*2+hi, l31) -> VT[df*32+l31][ (ks*2+hi)*8 ..+8 ]
// => every ds_read_b128 is contiguous per half-wave: ZERO bank conflicts,
//    zero address VALU (one base VGPR + immediate offsets).
// global_load_lds dest linear; per-lane GLOBAL source carries the inverse map.
// LDS: K dbuf 2x16KB @ [0,32KB) + VT dbuf 2x16KB @ [32KB,64KB).
// ---------------------------------------------------------------------------
__global__ __launch_bounds__(256, 2)
void relu2_attn_main(const float* __restrict__ q,
                     const short* __restrict__ kbf,
                     const short* __restrict__ vtbf,
                     const float* __restrict__ scale_p,
                     float* __restrict__ out) {
    __shared__ __align__(16) char lds[65536];

    const int tid  = threadIdx.x;
    const int wave = tid >> 6;
    const int lane = tid & 63;
    const int l31  = lane & 31;
    const int hi   = lane >> 5;          // 0/1

    const int bid = blockIdx.x;
    const int bh  = bid & 31;
    const int qt  = bid >> 5;
    const int q0  = qt * QT;

    const float* qb = q    + (size_t)bh * S_LEN * D_DIM;
    const short* kb = kbf  + (size_t)bh * S_LEN * D_DIM;
    const short* vt = vtbf + (size_t)bh * (size_t)D_DIM * S_LEN;
    float*       ob = out  + (size_t)bh * S_LEN * D_DIM;

    const float scale = scale_p[0];

    // single per-lane LDS read base (byte); all reads = base + imm offset
    const int RB = hi*512 + l31*16;

    // ---- staging source offsets (shorts), per chunk p: inverse fragment map
    int kOff[4], vOff[4];
    #pragma unroll
    for (int p = 0; p < 4; ++p) {
        const int s = (p*4 + wave)*64 + lane;          // dest slot (16B units)
        const int rK = ((s >> 9) << 5) | (s & 31);     // K row 0..63
        const int cK = (s >> 5) & 15;                  // K 16B-chunk
        kOff[p] = rK*128 + cK*8;
        const int dV = (((s >> 8) & 3) << 5) | (s & 31); // VT row (d) 0..127
        const int cV = (s >> 5) & 7;                   // VT 16B-chunk
        vOff[p] = dV*2048 + cV*8;
    }

    // ---- Q fragments: lane holds Q[q = wave*32+l31][d = dk*16 + hi*8 + e]
    bf16x8 qa[8];
    {
        const int qrow = q0 + wave*32 + l31;
        const float* qp = qb + (size_t)qrow * D_DIM + hi*8;
        #pragma unroll
        for (int dk = 0; dk < 8; ++dk) {
            f32x4 a = *(const f32x4*)(qp + dk*16);
            f32x4 c = *(const f32x4*)(qp + dk*16 + 4);
            bf16x8 t;
            t[0]=f2bf(a[0]*scale); t[1]=f2bf(a[1]*scale);
            t[2]=f2bf(a[2]*scale); t[3]=f2bf(a[3]*scale);
            t[4]=f2bf(c[0]*scale); t[5]=f2bf(c[1]*scale);
            t[6]=f2bf(c[2]*scale); t[7]=f2bf(c[3]*scale);
            qa[dk] = t;
        }
    }

    f32x16 oacc[4];
    #pragma unroll
    for (int df = 0; df < 4; ++df) oacc[df] = {};

// Stage tile T into buffer B: 16 K-chunks + 16 V-chunks of 1KB (4 per wave).
#define STAGE(T, B) do {                                                      \
    const int k0_ = (T) * KT;                                                 \
    _Pragma("unroll")                                                         \
    for (int p_ = 0; p_ < 4; ++p_) {                                          \
        const int ch_ = p_*4 + wave;                                          \
        gload_lds16(kb + k0_*128 + kOff[p_],                                  \
                    lds + (B)*16384 + ch_*1024);                              \
        gload_lds16(vt + k0_ + vOff[p_],                                      \
                    lds + 32768 + (B)*16384 + ch_*1024);                      \
    }                                                                         \
} while (0)

// One K-tile of compute from buffer BUF (compile-time 0/1).
#define TILE_COMPUTE(BUF) do {                                                \
    f32x16 s0 = {}, s1 = {};                                                  \
    __builtin_amdgcn_s_setprio(1);                                            \
    _Pragma("unroll")                                                         \
    for (int dk = 0; dk < 8; ++dk) {                                          \
        bf16x8 a0 = *(const bf16x8*)(lds + (BUF)*16384 + RB + (dk<<10));      \
        bf16x8 a1 = *(const bf16x8*)(lds + (BUF)*16384 + RB + (dk<<10) + 8192); \
        s0 = __builtin_amdgcn_mfma_f32_32x32x16_bf16(a0, qa[dk], s0, 0, 0, 0);\
        s1 = __builtin_amdgcn_mfma_f32_32x32x16_bf16(a1, qa[dk], s1, 0, 0, 0);\
    }                                                                         \
    __builtin_amdgcn_s_setprio(0);                                            \
    /* P = relu(S)^2 -> bf16 A-frags via cvt_pk + permlane32_swap */          \
    bf16x8 pa[4];                                                             \
    _Pragma("unroll")                                                         \
    for (int kf = 0; kf < 2; ++kf) {                                          \
        const f32x16 sv = kf ? s1 : s0;                                       \
        float pr[16];                                                         \
        _Pragma("unroll")                                                     \
        for (int r = 0; r < 16; ++r) {                                        \
            float m_ = fmaxf(sv[r], 0.f); pr[r] = m_ * m_;                    \
        }                                                                     \
        _Pragma("unroll")                                                     \
        for (int t2 = 0; t2 < 2; ++t2) {                                      \
            unsigned int X  = pk2(pr[8*t2+0], pr[8*t2+1]);                    \
            unsigned int Y  = pk2(pr[8*t2+4], pr[8*t2+5]);                    \
            unsigned int X2 = pk2(pr[8*t2+2], pr[8*t2+3]);                    \
            unsigned int Y2 = pk2(pr[8*t2+6], pr[8*t2+7]);                    \
            asm volatile("v_permlane32_swap_b32 %0, %1" : "+v"(X),  "+v"(Y)); \
            asm volatile("v_permlane32_swap_b32 %0, %1" : "+v"(X2), "+v"(Y2));\
            pa[kf*2 + t2] = __builtin_bit_cast(bf16x8, (uintx4){X, X2, Y, Y2});\
        }                                                                     \
    }                                                                         \
    __builtin_amdgcn_s_setprio(1);                                            \
    _Pragma("unroll")                                                         \
    for (int s_ = 0; s_ < 4; ++s_) {                                          \
        _Pragma("unroll")                                                     \
        for (int df = 0; df < 4; ++df) {                                      \
            bf16x8 vf = *(const bf16x8*)(lds + 32768 + (BUF)*16384 + RB       \
                                         + (df<<12) + (s_<<10));              \
            oacc[df] = __builtin_amdgcn_mfma_f32_32x32x16_bf16(pa[s_], vf, oacc[df], 0, 0, 0); \
        }                                                                     \
    }                                                                         \
    __builtin_amdgcn_s_setprio(0);                                            \
} while (0)

    STAGE(0, 0);

    #pragma unroll 1
    for (int p = 0; p < NT/2; ++p) {
        __syncthreads();                  // buf0 loads landed; buf1 free
        STAGE(2*p + 1, 1);
        TILE_COMPUTE(0);
        __syncthreads();                  // buf1 loads landed; buf0 free
        STAGE((2*p + 2) & (NT - 1), 0);   // last iter: harmless reload of t=0
        TILE_COMPUTE(1);
    }

    // ---- epilogue: O[q = rg*8 + hi*4 + e][d = df*32 + l31]
    #pragma unroll
    for (int df = 0; df < 4; ++df) {
        #pragma unroll
        for (int rg = 0; rg < 4; ++rg) {
            #pragma unroll
            for (int e = 0; e < 4; ++e) {
                const int row = q0 + wave*32 + rg*8 + hi*4 + e;
                ob[(size_t)row * D_DIM + df*32 + l31] = oacc[df][rg*4 + e];
            }
        }
    }
}

// ---------------------------------------------------------------------------
// Fallback (proven R2 kernel) if ws is too small for the bf16 side buffers.
// ---------------------------------------------------------------------------
#define KS 136
#define VS 72
#define PS 72

__global__ __launch_bounds__(256, 2)
void relu2_attn_fallback(const float* __restrict__ q,
                         const float* __restrict__ k,
                         const float* __restrict__ v,
                         const float* __restrict__ scale_p,
                         float* __restrict__ out) {
    __shared__ short Klds[KT][KS];
    __shared__ short VTlds[D_DIM][VS];
    __shared__ short Plds[QT][PS];

    const int tid  = threadIdx.x;
    const int wave = tid >> 6;
    const int lane = tid & 63;
    const int l15  = lane & 15;
    const int lg   = lane >> 4;

    const int bid = blockIdx.x;
    const int bh  = bid & 31;
    const int qt  = bid >> 5;
    const int q0  = qt * QT;

    const float* qb = q + (size_t)bh * S_LEN * D_DIM;
    const float* kb = k + (size_t)bh * S_LEN * D_DIM;
    const float* vb = v + (size_t)bh * S_LEN * D_DIM;
    float*       ob = out + (size_t)bh * S_LEN * D_DIM;

    const float scale = scale_p[0];

    bf16x8 qa[2][4];
    {
        const int qrow = q0 + wave * 32;
        #pragma unroll
        for (int qf = 0; qf < 2; ++qf) {
            const float* qp = qb + (size_t)(qrow + qf*16 + l15) * D_DIM + lg * 8;
            #pragma unroll
            for (int dk = 0; dk < 4; ++dk) {
                f32x4 a = *(const f32x4*)(qp + dk*32);
                f32x4 c = *(const f32x4*)(qp + dk*32 + 4);
                bf16x8 t;
                t[0]=f2bf(a[0]*scale); t[1]=f2bf(a[1]*scale);
                t[2]=f2bf(a[2]*scale); t[3]=f2bf(a[3]*scale);
                t[4]=f2bf(c[0]*scale); t[5]=f2bf(c[1]*scale);
                t[6]=f2bf(c[2]*scale); t[7]=f2bf(c[3]*scale);
                qa[qf][dk] = t;
            }
        }
    }

    const int kr = tid >> 4;
    const int kc = tid & 15;
    const int vd = tid & 127;
    const int vh = (tid >> 7) * 32;

    f32x4 kreg[8];
    float vreg[32];

#define FLOAD_TILE(T) do {                                                    \
    const float* kp_ = kb + (size_t)((T) * KT) * D_DIM;                       \
    _Pragma("unroll")                                                         \
    for (int p = 0; p < 4; ++p) {                                             \
        const float* rp_ = kp_ + (size_t)(p*16 + kr) * D_DIM + kc*8;          \
        kreg[2*p]   = *(const f32x4*)rp_;                                     \
        kreg[2*p+1] = *(const f32x4*)(rp_ + 4);                               \
    }                                                                         \
    const float* vp_ = vb + (size_t)((T) * KT + vh) * D_DIM + vd;             \
    _Pragma("unroll")                                                         \
    for (int j = 0; j < 32; ++j) vreg[j] = vp_[(size_t)j * D_DIM];            \
} while (0)

#define FSTORE_TILE() do {                                                    \
    _Pragma("unroll")                                                         \
    for (int p = 0; p < 4; ++p) {                                             \
        f32x4 a_ = kreg[2*p], b_ = kreg[2*p+1];                               \
        bf16x8 w_;                                                            \
        w_[0]=f2bf(a_[0]); w_[1]=f2bf(a_[1]); w_[2]=f2bf(a_[2]); w_[3]=f2bf(a_[3]); \
        w_[4]=f2bf(b_[0]); w_[5]=f2bf(b_[1]); w_[6]=f2bf(b_[2]); w_[7]=f2bf(b_[3]); \
        *(bf16x8*)&Klds[p*16 + kr][kc*8] = w_;                                \
    }                                                                         \
    _Pragma("unroll")                                                         \
    for (int c = 0; c < 4; ++c) {                                             \
        bf16x8 w_;                                                            \
        w_[0]=f2bf(vreg[c*8+0]); w_[1]=f2bf(vreg[c*8+1]);                     \
        w_[2]=f2bf(vreg[c*8+2]); w_[3]=f2bf(vreg[c*8+3]);                     \
        w_[4]=f2bf(vreg[c*8+4]); w_[5]=f2bf(vreg[c*8+5]);                     \
        w_[6]=f2bf(vreg[c*8+6]); w_[7]=f2bf(vreg[c*8+7]);                     \
        *(bf16x8*)&VTlds[vd][vh + c*8] = w_;                                  \
    }                                                                         \
} while (0)

    f32x4 oacc[2][8];
    #pragma unroll
    for (int i = 0; i < 2; ++i)
        #pragma unroll
        for (int j = 0; j < 8; ++j)
            oacc[i][j] = f32x4{0.f, 0.f, 0.f, 0.f};

    FLOAD_TILE(0);

    for (int t = 0; t < NT; ++t) {
        FSTORE_TILE();
        __syncthreads();
        FLOAD_TILE((t + 1) & (NT - 1));

        f32x4 sacc[2][4];
        #pragma unroll
        for (int qf = 0; qf < 2; ++qf)
            #pragma unroll
            for (int kf = 0; kf < 4; ++kf)
                sacc[qf][kf] = f32x4{0.f, 0.f, 0.f, 0.f};

        #pragma unroll
        for (int dk = 0; dk < 4; ++dk) {
            #pragma unroll
            for (int kf = 0; kf < 4; ++kf) {
                bf16x8 bf = *(const bf16x8*)&Klds[kf*16 + l15][dk*32 + lg*8];
                #pragma unroll
                for (int qf = 0; qf < 2; ++qf)
                    sacc[qf][kf] = __builtin_amdgcn_mfma_f32_16x16x32_bf16(
                        qa[qf][dk], bf, sacc[qf][kf], 0, 0, 0);
            }
        }

        #pragma unroll
        for (int qf = 0; qf < 2; ++qf) {
            #pragma unroll
            for (int kf = 0; kf < 4; ++kf) {
                f32x4 sv = sacc[qf][kf];
                #pragma unroll
                for (int e = 0; e < 4; ++e) {
                    float r = fmaxf(sv[e], 0.f);
                    Plds[wave*32 + qf*16 + lg*4 + e][kf*16 + l15] = f2bf(r * r);
                }
            }
        }

        #pragma unroll
        for (int ks = 0; ks < 2; ++ks) {
            bf16x8 pa[2];
            #pragma unroll
            for (int qf = 0; qf < 2; ++qf)
                pa[qf] = *(const bf16x8*)&Plds[wave*32 + qf*16 + l15][ks*32 + lg*8];
            #pragma unroll
            for (int df = 0; df < 8; ++df) {
                bf16x8 vf = *(const bf16x8*)&VTlds[df*16 + l15][ks*32 + lg*8];
                #pragma unroll
                for (int qf = 0; qf < 2; ++qf)
                    oacc[qf][df] = __builtin_amdgcn_mfma_f32_16x16x32_bf16(
                        pa[qf], vf, oacc[qf][df], 0, 0, 0);
            }
        }
        __syncthreads();
    }

    #pragma unroll
    for (int qf = 0; qf < 2; ++qf) {
        #pragma unroll
        for (int df = 0; df < 8; ++df) {
            f32x4 o = oacc[qf][df];
            const int row = q0 + wave*32 + qf*16 + lg*4;
            float* op = ob + (size_t)row * D_DIM + df*16 + l15;
            op[0*D_DIM] = o[0];
            op[1*D_DIM] = o[1];
            op[2*D_DIM] = o[2];
            op[3*D_DIM] = o[3];
        }
    }
}

extern "C" void kernel_launch(void* const* d_in, const int* in_sizes, int n_in,
                              void* d_out, int out_size, void* d_ws, size_t ws_size,
                              hipStream_t stream) {
    const float* q = (const float*)d_in[0];
    const float* k = (const float*)d_in[1];
    const float* v = (const float*)d_in[2];
    const float* scale = (const float*)d_in[3];
    float* out = (float*)d_out;

    const size_t elems = (size_t)2 * 16 * S_LEN * D_DIM;   // 8.39M per tensor
    const size_t need  = elems * 2 * 2;                    // K + VT bf16 bytes

    if (ws_size >= need) {
        short* kbf = (short*)d_ws;
        short* vtb = (short*)d_ws + elems;
        convert_k_kernel<<<dim3((int)(elems / (256 * 8))), dim3(256), 0, stream>>>(k, kbf);
        transpose_v_kernel<<<dim3(256), dim3(256), 0, stream>>>(v, vtb);
        relu2_attn_main<<<dim3(512), dim3(256), 0, stream>>>(q, kbf, vtb, scale, out);
    } else {
        relu2_attn_fallback<<<dim3(512), dim3(256), 0, stream>>>(q, k, v, scale, out);
    }
}